// Round 1
// baseline (81.036 us; speedup 1.0000x reference)
//
#include <hip/hip_runtime.h>

// Active-set water-filling projection, one 64-lane wave per row.
// Row state (16 y, 16 upper, 16 zc floats + 16-bit mask per lane) lives
// entirely in registers; reductions via __shfl_xor butterflies; early exit
// when phase==2 (bit-equivalent to the reference's fixed 32 rounds, since
// the scan state is frozen once phase==2).

#define N_COLS 1024
#define NBIKES 512.0f

__global__ __launch_bounds__(256) void proj_rows(
    const float* __restrict__ y,
    const float* __restrict__ upper,
    float* __restrict__ out,
    int B)
{
    const int lane = threadIdx.x & 63;
    const int wave = threadIdx.x >> 6;
    const int row  = (blockIdx.x << 2) + wave;
    if (row >= B) return;

    const float* yrow = y + (size_t)row * N_COLS;

    // Each lane owns 16 elements as 4 float4 chunks: element = j*256 + 4*lane + k
    float4 yv[4], uv[4], zc[4];
#pragma unroll
    for (int j = 0; j < 4; ++j) {
        const int idx = (j << 8) + (lane << 2);
        yv[j] = *reinterpret_cast<const float4*>(yrow + idx);
        uv[j] = *reinterpret_cast<const float4*>(upper + idx);
        zc[j] = make_float4(0.f, 0.f, 0.f, 0.f);
    }

    unsigned mask = 0xFFFFu;   // bit b = 1 => element unclamped
    float C = NBIKES;
    int phase = 0;

    for (int it = 0; it < 32 && phase < 2; ++it) {
        // --- reduction 1: n_un = sum(m), s = sum(m ? y : 0) ---
        float n_un = 0.f, s = 0.f;
#pragma unroll
        for (int j = 0; j < 4; ++j) {
            const float* yp = reinterpret_cast<const float*>(&yv[j]);
#pragma unroll
            for (int k = 0; k < 4; ++k) {
                if ((mask >> ((j << 2) + k)) & 1u) { n_un += 1.f; s += yp[k]; }
            }
        }
#pragma unroll
        for (int off = 32; off >= 1; off >>= 1) {
            n_un += __shfl_xor(n_un, off, 64);
            s    += __shfl_xor(s,    off, 64);
        }
        const float t = (C - s) / fmaxf(n_un, 1.0f);

        // --- clamp violators ---
        bool lane_viol = false;
        float csum = 0.f;   // sum of newly-clamped values (0 in phase 0)
#pragma unroll
        for (int j = 0; j < 4; ++j) {
            const float* yp = reinterpret_cast<const float*>(&yv[j]);
            const float* up = reinterpret_cast<const float*>(&uv[j]);
            float* zp = reinterpret_cast<float*>(&zc[j]);
#pragma unroll
            for (int k = 0; k < 4; ++k) {
                const int b = (j << 2) + k;
                if (!((mask >> b) & 1u)) continue;
                const float z = yp[k] + t;
                const bool v = (phase == 0) ? (z < 0.f) : (z > up[k]);
                if (v) {
                    const float cv = (phase == 0) ? 0.f : up[k];
                    zp[k]  = cv;
                    csum  += cv;
                    mask  &= ~(1u << b);
                    lane_viol = true;
                }
            }
        }

        if (phase == 1) {   // phase-0 clamp value is 0 => C unchanged, skip reduction
#pragma unroll
            for (int off = 32; off >= 1; off >>= 1)
                csum += __shfl_xor(csum, off, 64);
            C -= csum;
        }
        if (!__any((int)lane_viol)) ++phase;
    }

    // --- final water-fill over the surviving unclamped set ---
    float n_un = 0.f, s = 0.f;
#pragma unroll
    for (int j = 0; j < 4; ++j) {
        const float* yp = reinterpret_cast<const float*>(&yv[j]);
#pragma unroll
        for (int k = 0; k < 4; ++k)
            if ((mask >> ((j << 2) + k)) & 1u) { n_un += 1.f; s += yp[k]; }
    }
#pragma unroll
    for (int off = 32; off >= 1; off >>= 1) {
        n_un += __shfl_xor(n_un, off, 64);
        s    += __shfl_xor(s,    off, 64);
    }
    const float t = (C - s) / fmaxf(n_un, 1.0f);

    float* orow = out + (size_t)row * N_COLS;
#pragma unroll
    for (int j = 0; j < 4; ++j) {
        const float* yp = reinterpret_cast<const float*>(&yv[j]);
        const float* zp = reinterpret_cast<const float*>(&zc[j]);
        float4 o;
        float* op = reinterpret_cast<float*>(&o);
#pragma unroll
        for (int k = 0; k < 4; ++k) {
            const int b = (j << 2) + k;
            op[k] = ((mask >> b) & 1u) ? (yp[k] + t) : zp[k];
        }
        *reinterpret_cast<float4*>(orow + (j << 8) + (lane << 2)) = o;
    }
}

extern "C" void kernel_launch(void* const* d_in, const int* in_sizes, int n_in,
                              void* d_out, int out_size, void* d_ws, size_t ws_size,
                              hipStream_t stream) {
    const float* yv    = (const float*)d_in[0];
    const float* upper = (const float*)d_in[1];
    float* out = (float*)d_out;
    const int B = in_sizes[0] / N_COLS;        // 2048
    const int blocks = (B + 3) >> 2;           // 4 rows (waves) per 256-thread block
    proj_rows<<<blocks, 256, 0, stream>>>(yv, upper, out, B);
}

// Round 2
// 66.997 us; speedup vs baseline: 1.2096x; 1.2096x over previous
//
#include <hip/hip_runtime.h>

// Active-set water-filling projection, one 64-lane wave per row.
// Round-level reductions use DPP (VALU pipe, ~10 cyc/step) instead of
// ds_bpermute shuffles (~120 cyc/step), and the per-round state update is
// incremental: d = C - s and n are wave scalars, only the per-round deltas
// (sum of cval - y over newly clamped, count) are reduced — ONE dual DPP
// reduction per round.

#define N_COLS 1024
#define NBIKES 512.0f

// x += dpp_moved(x) for two independent accumulators (ILP-paired chains).
#define DPP_ADD2(ctrl)                                                                         \
    a += __int_as_float(__builtin_amdgcn_update_dpp(0, __float_as_int(a), (ctrl), 0xf, 0xf, true)); \
    b += __int_as_float(__builtin_amdgcn_update_dpp(0, __float_as_int(b), (ctrl), 0xf, 0xf, true));

// Full 64-lane sum of a and b; result broadcast to all lanes (via readlane->SGPR).
__device__ __forceinline__ void wave_sum2(float& a, float& b) {
    DPP_ADD2(0x111)   // row_shr:1
    DPP_ADD2(0x112)   // row_shr:2
    DPP_ADD2(0x114)   // row_shr:4
    DPP_ADD2(0x118)   // row_shr:8  -> lane 15/31/47/63 hold their row-of-16 sums
    DPP_ADD2(0x142)   // row_bcast:15 -> lane31 = rows0+1, lane63 = rows2+3
    DPP_ADD2(0x143)   // row_bcast:31 -> lane63 = full wave sum
    a = __int_as_float(__builtin_amdgcn_readlane(__float_as_int(a), 63));
    b = __int_as_float(__builtin_amdgcn_readlane(__float_as_int(b), 63));
}

__global__ __launch_bounds__(256) void proj_rows(
    const float* __restrict__ y,
    const float* __restrict__ upper,
    float* __restrict__ out,
    int B)
{
    const int lane = threadIdx.x & 63;
    const int wave = threadIdx.x >> 6;
    const int row  = (blockIdx.x << 2) + wave;
    if (row >= B) return;

    const float* yrow = y + (size_t)row * N_COLS;

    // Each lane owns 16 elements as 4 float4 chunks: element = j*256 + 4*lane + k
    float4 yv[4], uv[4];
#pragma unroll
    for (int j = 0; j < 4; ++j) {
        const int idx = (j << 8) + (lane << 2);
        yv[j] = *reinterpret_cast<const float4*>(yrow + idx);
        uv[j] = *reinterpret_cast<const float4*>(upper + idx);
    }

    // Initial s = sum(y) over the whole row (all elements unclamped).
    float s_part = 0.f, zero = 0.f;
#pragma unroll
    for (int j = 0; j < 4; ++j) {
        const float* yp = reinterpret_cast<const float*>(&yv[j]);
#pragma unroll
        for (int k = 0; k < 4; ++k) s_part += yp[k];
    }
    wave_sum2(s_part, zero);

    float d = NBIKES - s_part;   // d = C - s  (wave-uniform scalar)
    float n = (float)N_COLS;     // unclamped count
    unsigned alive = 0xFFFFu;    // bit b = 1 => element unclamped
    unsigned hi    = 0u;         // bit b = 1 => clamped at upper (phase 1)
    int phase = 0;

    for (int it = 0; it < 32 && phase < 2; ++it) {
        const float t = d / fmaxf(n, 1.0f);
        float delta = 0.f;   // sum over newly clamped of (cval - y)
        float cnt   = 0.f;   // newly clamped count

        if (phase == 0) {            // wave-uniform branch
#pragma unroll
            for (int j = 0; j < 4; ++j) {
                const float* yp = reinterpret_cast<const float*>(&yv[j]);
#pragma unroll
                for (int k = 0; k < 4; ++k) {
                    const int b = (j << 2) + k;
                    const bool v = ((alive >> b) & 1u) && (yp[k] + t < 0.f);
                    if (v) { delta -= yp[k]; cnt += 1.f; alive &= ~(1u << b); }
                }
            }
        } else {                     // phase == 1
#pragma unroll
            for (int j = 0; j < 4; ++j) {
                const float* yp = reinterpret_cast<const float*>(&yv[j]);
                const float* up = reinterpret_cast<const float*>(&uv[j]);
#pragma unroll
                for (int k = 0; k < 4; ++k) {
                    const int b = (j << 2) + k;
                    const bool v = ((alive >> b) & 1u) && (yp[k] + t > up[k]);
                    if (v) {
                        delta += up[k] - yp[k];
                        cnt   += 1.f;
                        alive &= ~(1u << b);
                        hi    |= (1u << b);
                    }
                }
            }
        }

        wave_sum2(delta, cnt);
        d -= delta;
        n -= cnt;
        if (cnt == 0.f) ++phase;     // wave-uniform (cnt is a broadcast scalar)
    }

    const float t = d / fmaxf(n, 1.0f);

    float* orow = out + (size_t)row * N_COLS;
#pragma unroll
    for (int j = 0; j < 4; ++j) {
        const float* yp = reinterpret_cast<const float*>(&yv[j]);
        const float* up = reinterpret_cast<const float*>(&uv[j]);
        float4 o;
        float* op = reinterpret_cast<float*>(&o);
#pragma unroll
        for (int k = 0; k < 4; ++k) {
            const int b = (j << 2) + k;
            op[k] = ((alive >> b) & 1u) ? (yp[k] + t)
                   : (((hi >> b) & 1u) ? up[k] : 0.f);
        }
        *reinterpret_cast<float4*>(orow + (j << 8) + (lane << 2)) = o;
    }
}

extern "C" void kernel_launch(void* const* d_in, const int* in_sizes, int n_in,
                              void* d_out, int out_size, void* d_ws, size_t ws_size,
                              hipStream_t stream) {
    const float* yv    = (const float*)d_in[0];
    const float* upper = (const float*)d_in[1];
    float* out = (float*)d_out;
    const int B = in_sizes[0] / N_COLS;        // 2048
    const int blocks = (B + 3) >> 2;           // 4 rows (waves) per 256-thread block
    proj_rows<<<blocks, 256, 0, stream>>>(yv, upper, out, B);
}

// Round 3
// 66.856 us; speedup vs baseline: 1.2121x; 1.0021x over previous
//
#include <hip/hip_runtime.h>

// Active-set water-filling projection, one 64-lane wave per row.
// Per-round: dual DPP reduction (VALU pipe) of stateless per-lane partials
//   a = sp + uc   (sp = sum of alive y, uc = sum of upper over hi-clamped)
//   b = popc(alive)
// then t = (C - A) * rcp(B), one branchless 16-element scan, __any vote.
// Phase transition is fused: when phase 0 finds no violators, the upper scan
// runs in the SAME round with the same t (bit-equivalent to the reference,
// whose extra round recomputes an identical t from unchanged state).

#define N_COLS 1024
#define NBIKES 512.0f

// x += dpp_moved(x) for two independent accumulators (ILP-paired chains).
#define DPP_ADD2(ctrl)                                                                         \
    a += __int_as_float(__builtin_amdgcn_update_dpp(0, __float_as_int(a), (ctrl), 0xf, 0xf, true)); \
    b += __int_as_float(__builtin_amdgcn_update_dpp(0, __float_as_int(b), (ctrl), 0xf, 0xf, true));

// Full 64-lane sum of a and b; result broadcast to all lanes via readlane.
__device__ __forceinline__ void wave_sum2(float& a, float& b) {
    DPP_ADD2(0x111)   // row_shr:1
    DPP_ADD2(0x112)   // row_shr:2
    DPP_ADD2(0x114)   // row_shr:4
    DPP_ADD2(0x118)   // row_shr:8  -> lanes 15/31/47/63 hold row-of-16 sums
    DPP_ADD2(0x142)   // row_bcast:15
    DPP_ADD2(0x143)   // row_bcast:31 -> lane 63 = full wave sum
    a = __int_as_float(__builtin_amdgcn_readlane(__float_as_int(a), 63));
    b = __int_as_float(__builtin_amdgcn_readlane(__float_as_int(b), 63));
}

__global__ __launch_bounds__(256) void proj_rows(
    const float* __restrict__ y,
    const float* __restrict__ upper,
    float* __restrict__ out,
    int B)
{
    const int lane = threadIdx.x & 63;
    const int wave = threadIdx.x >> 6;
    const int row  = (blockIdx.x << 2) + wave;
    if (row >= B) return;

    const float* yrow = y + (size_t)row * N_COLS;

    // Each lane owns 16 elements as 4 float4 chunks: element = j*256 + 4*lane + k
    float4 yv[4], uv[4];
#pragma unroll
    for (int j = 0; j < 4; ++j) {
        const int idx = (j << 8) + (lane << 2);
        yv[j] = *reinterpret_cast<const float4*>(yrow + idx);
        uv[j] = *reinterpret_cast<const float4*>(upper + idx);
    }

    // Per-lane partials (stateless w.r.t. the wave scalar t):
    float sp = 0.f;              // sum of y over alive elements in this lane
    float uc = 0.f;              // sum of upper over hi-clamped elements
#pragma unroll
    for (int j = 0; j < 4; ++j) {
        const float* yp = reinterpret_cast<const float*>(&yv[j]);
#pragma unroll
        for (int k = 0; k < 4; ++k) sp += yp[k];
    }

    unsigned alive = 0xFFFFu;    // bit b = 1 => unclamped
    unsigned hi    = 0u;         // bit b = 1 => clamped at upper
    int phase = 0;
    float t = 0.f;

    for (int it = 0; it < 32; ++it) {
        float a = sp + uc;
        float b = (float)__popc(alive);
        wave_sum2(a, b);
        t = (NBIKES - a) * __builtin_amdgcn_rcpf(fmaxf(b, 1.0f));

        if (phase == 0) {        // wave-uniform branch
            bool viol = false;
#pragma unroll
            for (int j = 0; j < 4; ++j) {
                const float* yp = reinterpret_cast<const float*>(&yv[j]);
#pragma unroll
                for (int k = 0; k < 4; ++k) {
                    const unsigned bit = 1u << ((j << 2) + k);
                    if ((alive & bit) && (yp[k] + t < 0.f)) {
                        sp -= yp[k]; alive &= ~bit; viol = true;
                    }
                }
            }
            if (__any((int)viol)) continue;   // more lower clamps next round
            phase = 1;                        // fused transition: same t, scan upper now
        }

        bool viol = false;
#pragma unroll
        for (int j = 0; j < 4; ++j) {
            const float* yp = reinterpret_cast<const float*>(&yv[j]);
            const float* up = reinterpret_cast<const float*>(&uv[j]);
#pragma unroll
            for (int k = 0; k < 4; ++k) {
                const unsigned bit = 1u << ((j << 2) + k);
                if ((alive & bit) && (yp[k] + t > up[k])) {
                    sp -= yp[k]; uc += up[k];
                    alive &= ~bit; hi |= bit; viol = true;
                }
            }
        }
        if (!__any((int)viol)) break;         // converged: t is final water level
    }

    // Final water-fill (state unchanged since last reduction => t already final,
    // but recompute to mirror the reference's final step exactly).
    {
        float a = sp + uc;
        float b = (float)__popc(alive);
        wave_sum2(a, b);
        t = (NBIKES - a) * __builtin_amdgcn_rcpf(fmaxf(b, 1.0f));
    }

    float* orow = out + (size_t)row * N_COLS;
#pragma unroll
    for (int j = 0; j < 4; ++j) {
        const float* yp = reinterpret_cast<const float*>(&yv[j]);
        const float* up = reinterpret_cast<const float*>(&uv[j]);
        float4 o;
        float* op = reinterpret_cast<float*>(&o);
#pragma unroll
        for (int k = 0; k < 4; ++k) {
            const unsigned bit = 1u << ((j << 2) + k);
            op[k] = (alive & bit) ? (yp[k] + t) : ((hi & bit) ? up[k] : 0.f);
        }
        *reinterpret_cast<float4*>(orow + (j << 8) + (lane << 2)) = o;
    }
}

extern "C" void kernel_launch(void* const* d_in, const int* in_sizes, int n_in,
                              void* d_out, int out_size, void* d_ws, size_t ws_size,
                              hipStream_t stream) {
    const float* yv    = (const float*)d_in[0];
    const float* upper = (const float*)d_in[1];
    float* out = (float*)d_out;
    const int B = in_sizes[0] / N_COLS;        // 2048
    const int blocks = (B + 3) >> 2;           // 4 rows (waves) per 256-thread block
    proj_rows<<<blocks, 256, 0, stream>>>(yv, upper, out, B);
}